// Round 4
// baseline (968.855 us; speedup 1.0000x reference)
//
#include <hip/hip_runtime.h>
#include <cstdint>
#include <cstddef>

typedef float f32x4 __attribute__((ext_vector_type(4)));
typedef __bf16 bf16x8 __attribute__((ext_vector_type(8)));

__device__ __forceinline__ unsigned short f2bf(float f) {
    unsigned int u = __float_as_uint(f);
    u += 0x7fffu + ((u >> 16) & 1u);   // round-to-nearest-even
    return (unsigned short)(u >> 16);
}

__device__ __forceinline__ void async_copy16(const void* g, void* l) {
    __builtin_amdgcn_global_load_lds(
        (__attribute__((address_space(1))) void*)(g),
        (__attribute__((address_space(3))) void*)(l), 16, 0, 0);
}

// ---------------- fused prep kernel ----------------
// blocks [0,16384): cast x fp32->bf16 (8192x4096)
// blocks [16384,16896): dequant L -> Ld [4096][256]
// blocks [16896,17408): dequant R + transpose -> Rt [4096][256]
__global__ void prep_kernel(const float* __restrict__ x,
                            unsigned short* __restrict__ xb,
                            const int* __restrict__ lv,
                            const float* __restrict__ ls,
                            unsigned short* __restrict__ Ld,
                            const int* __restrict__ rv,
                            const float* __restrict__ rs,
                            unsigned short* __restrict__ Rt) {
    const int bid = blockIdx.x;
    const int tid = threadIdx.x;
    if (bid < 16384) {
        const int i = bid * 256 + tid;
        const float4* xv = (const float4*)x;
        float4 a = xv[2 * (size_t)i];
        float4 b = xv[2 * (size_t)i + 1];
        union { unsigned short u[8]; uint4 v; } r;
        r.u[0] = f2bf(a.x); r.u[1] = f2bf(a.y); r.u[2] = f2bf(a.z); r.u[3] = f2bf(a.w);
        r.u[4] = f2bf(b.x); r.u[5] = f2bf(b.y); r.u[6] = f2bf(b.z); r.u[7] = f2bf(b.w);
        ((uint4*)xb)[i] = r.v;
    } else if (bid < 16896) {
        const int i = (bid - 16384) * 256 + tid;     // 0..131071
        const int e = i * 8;
        const int row = e >> 8;
        const int col = e & 255;
        const float sc = ls[row * 2 + (col >> 7)];
        int4 a = ((const int4*)lv)[2 * (size_t)i];
        int4 b = ((const int4*)lv)[2 * (size_t)i + 1];
        union { unsigned short u[8]; uint4 v; } r;
        r.u[0] = f2bf(a.x * sc); r.u[1] = f2bf(a.y * sc);
        r.u[2] = f2bf(a.z * sc); r.u[3] = f2bf(a.w * sc);
        r.u[4] = f2bf(b.x * sc); r.u[5] = f2bf(b.y * sc);
        r.u[6] = f2bf(b.z * sc); r.u[7] = f2bf(b.w * sc);
        ((uint4*)Ld)[i] = r.v;
    } else {
        const int g = (bid - 16896) * 256 + tid;     // 0..131071
        const int i  = g & 4095;
        const int r0 = (g >> 12) << 3;               // 0,8,...,248
        const int grp = i >> 7;
        union { unsigned short u[8]; uint4 v; } w;
        #pragma unroll
        for (int k = 0; k < 8; ++k) {
            const int r = r0 + k;
            const float sc = rs[r * 32 + grp];
            w.u[k] = f2bf((float)rv[(size_t)r * 4096 + i] * sc);
        }
        *(uint4*)&Rt[(size_t)i * 256 + r0] = w.v;
    }
}

// ---------------- 256x256 8-phase pipelined GEMM core (ROTATED) ----------------
// Round-4: phase body rotated to [lgkm(0); MFMA(q_p); reads(q_{p+1}); STAGE; bar]
// so ds_reads issue one phase ahead and execute under the MFMA cluster; the
// top-of-phase lgkm(0) finds them complete (no drain bubble, no read window on
// the critical path). Fragment register double-buffers: aLo/aHi single
// (lifetimes disjoint across slots), bLo duplicated (bLo0/bLo1 overlap p3-p4),
// bHi single. Residency checkpoints move to p3/p7 as vmcnt(2) AFTER MFMA and
// BEFORE the cross-slot reads: retires exactly through A1 of the tile those
// reads consume (2-phase DMA margin). WAR ledger: every overwriting STAGE
// issues >=2 barriers after its victims' read-issue. Prologue pre-issues the
// p1 reads after vmcnt(6)+barrier. sched_barrier(0) after each lgkm pins
// MFMAs below the wait (rule 18).

#define SM_OFF(slot_, mat_, half_) ((((slot_) * 2 + (mat_)) * 2 + (half_)) * 8192)

#define MFMA_QUAD(MG, NG, AA, BB)                                           \
    _Pragma("unroll")                                                       \
    for (int m_ = 0; m_ < 4; ++m_)                                          \
        _Pragma("unroll")                                                   \
        for (int n_ = 0; n_ < 2; ++n_)                                      \
            _Pragma("unroll")                                               \
            for (int k_ = 0; k_ < 2; ++k_)                                  \
                acc[(MG)*4 + m_][(NG)*2 + n_] =                             \
                    __builtin_amdgcn_mfma_f32_16x16x32_bf16(                \
                        AA[m_][k_], BB[n_][k_],                             \
                        acc[(MG)*4 + m_][(NG)*2 + n_], 0, 0, 0)

#define RD_A(dst_, src_, base_)                                             \
    _Pragma("unroll")                                                       \
    for (int m_ = 0; m_ < 4; ++m_) {                                        \
        dst_[m_][0] = *(const bf16x8*)((src_) + ((base_) + m_) * 1024 + aoff0); \
        dst_[m_][1] = *(const bf16x8*)((src_) + ((base_) + m_) * 1024 + aoff1); \
    }

#define RD_B(dst_, src_, base_)                                             \
    _Pragma("unroll")                                                       \
    for (int n_ = 0; n_ < 2; ++n_) {                                        \
        dst_[n_][0] = *(const bf16x8*)((src_) + ((base_) + n_) * 1024 + aoff0); \
        dst_[n_][1] = *(const bf16x8*)((src_) + ((base_) + n_) * 1024 + aoff1); \
    }

#define PH_TOP()                                                            \
    asm volatile("s_waitcnt lgkmcnt(0)" ::: "memory");                      \
    __builtin_amdgcn_sched_barrier(0)

#define PH_END() __builtin_amdgcn_s_barrier()

__device__ __forceinline__ void run_pipeline(
    const __bf16* __restrict__ A, const __bf16* __restrict__ B,
    const int lda, const int nt,
    const int mBase, const int nBase,
    const int wave, const int lane, const int wr, const int wc,
    __bf16* smp, f32x4 (&acc)[8][4])
{
    const int lrow  = lane >> 3;
    const int lcol  = (((lane & 7) ^ lrow) & 7) * 8;
    const int soff0 = (wave * 8 + lrow) * lda + lcol;
    const size_t dsoff = (size_t)64 * lda;           // second-load lane delta

    const __bf16* gA0 = A + (size_t)mBase * lda + soff0;
    const __bf16* gA1 = gA0 + (size_t)128 * lda;
    const __bf16* gB0 = B + (size_t)nBase * lda + soff0;
    const __bf16* gB1 = gB0 + (size_t)128 * lda;

    const int aoff0 = (lane & 15) * 64 + ((((lane >> 4))     ^ (lane & 7)) * 8);
    const int aoff1 = (lane & 15) * 64 + (((4 + (lane >> 4)) ^ (lane & 7)) * 8);

    const __bf16* Ah0 = smp + SM_OFF(0, 0, wr);
    const __bf16* Ah1 = smp + SM_OFF(1, 0, wr);
    const __bf16* Bh0 = smp + SM_OFF(0, 1, wc >> 1) + (wc & 1) * 4096;
    const __bf16* Bh1 = smp + SM_OFF(1, 1, wc >> 1) + (wc & 1) * 4096;

#define STAGE(gp_, tile_, slot_, mat_, half_) do {                           \
        const __bf16* g_ = (gp_) + (size_t)(tile_) * 64;                     \
        __bf16* d_ = smp + SM_OFF(slot_, mat_, half_);                       \
        async_copy16(g_,         d_ + wave * 512);                           \
        async_copy16(g_ + dsoff, d_ + (wave + 8) * 512);                     \
    } while (0)

    // prologue: tile0 [B0,B1,A0,A1], tile1 [B0,B1,A0] = 7 halves (14 loads)
    STAGE(gB0, 0, 0, 1, 0);
    STAGE(gB1, 0, 0, 1, 1);
    STAGE(gA0, 0, 0, 0, 0);
    STAGE(gA1, 0, 0, 0, 1);
    STAGE(gB0, 1, 1, 1, 0);
    STAGE(gB1, 1, 1, 1, 1);
    STAGE(gA0, 1, 1, 0, 0);
    asm volatile("s_waitcnt vmcnt(6)" ::: "memory");   // tile0 fully resident
    __builtin_amdgcn_s_barrier();

    bf16x8 aLo[4][2], aHi[4][2], bLo0[2][2], bLo1[2][2], bHi[2][2];

    // pre-issue phase-1 reads (t0, slot0)
    RD_A(aLo, Ah0, 0);
    RD_B(bLo0, Bh0, 0);

    const int niter = nt >> 1;
    #pragma unroll 1
    for (int i = 0; i < niter; ++i) {
        const int t1 = 2 * i + 1;
        int p2 = 2 * i + 2; if (p2 >= nt) p2 = nt - 2;   // even -> slot0
        int p3 = 2 * i + 3; if (p3 >= nt) p3 = nt - 1;   // odd  -> slot1

        // ---- phase 1: q00(t0) ----
        PH_TOP();
        __builtin_amdgcn_s_setprio(1);
        MFMA_QUAD(0, 0, aLo, bLo0);
        __builtin_amdgcn_s_setprio(0);
        RD_B(bHi, Bh0, 2);
        STAGE(gA1, t1, 1, 0, 1);
        PH_END();

        // ---- phase 2: q01(t0) ----
        PH_TOP();
        __builtin_amdgcn_s_setprio(1);
        MFMA_QUAD(0, 1, aLo, bHi);
        __builtin_amdgcn_s_setprio(0);
        RD_A(aHi, Ah0, 4);
        STAGE(gB0, p2, 0, 1, 0);
        PH_END();

        // ---- phase 3: q11(t0) + checkpoint + t1 low reads ----
        PH_TOP();
        __builtin_amdgcn_s_setprio(1);
        MFMA_QUAD(1, 1, aHi, bHi);
        __builtin_amdgcn_s_setprio(0);
        asm volatile("s_waitcnt vmcnt(2)" ::: "memory");  // t1 fully resident
        RD_A(aLo, Ah1, 0);
        RD_B(bLo1, Bh1, 0);
        STAGE(gB1, p2, 0, 1, 1);
        PH_END();

        // ---- phase 4: q10(t0) ----
        PH_TOP();
        __builtin_amdgcn_s_setprio(1);
        MFMA_QUAD(1, 0, aHi, bLo0);
        __builtin_amdgcn_s_setprio(0);
        RD_B(bHi, Bh1, 2);
        STAGE(gA0, p2, 0, 0, 0);
        PH_END();

        // ---- phase 5: q00(t1) ----
        PH_TOP();
        __builtin_amdgcn_s_setprio(1);
        MFMA_QUAD(0, 0, aLo, bLo1);
        __builtin_amdgcn_s_setprio(0);
        RD_A(aHi, Ah1, 4);
        STAGE(gA1, p2, 0, 0, 1);
        PH_END();

        // ---- phase 6: q01(t1) ----
        PH_TOP();
        __builtin_amdgcn_s_setprio(1);
        MFMA_QUAD(0, 1, aLo, bHi);
        __builtin_amdgcn_s_setprio(0);
        STAGE(gB0, p3, 1, 1, 0);
        PH_END();

        // ---- phase 7: q11(t1) + checkpoint + next-t0 low reads ----
        PH_TOP();
        __builtin_amdgcn_s_setprio(1);
        MFMA_QUAD(1, 1, aHi, bHi);
        __builtin_amdgcn_s_setprio(0);
        asm volatile("s_waitcnt vmcnt(2)" ::: "memory");  // next t0 resident
        RD_A(aLo, Ah0, 0);
        RD_B(bLo0, Bh0, 0);
        STAGE(gB1, p3, 1, 1, 1);
        PH_END();

        // ---- phase 8: q10(t1) ----
        PH_TOP();
        __builtin_amdgcn_s_setprio(1);
        MFMA_QUAD(1, 0, aHi, bLo1);
        __builtin_amdgcn_s_setprio(0);
        STAGE(gA0, p3, 1, 0, 0);
        PH_END();
    }

    asm volatile("s_waitcnt vmcnt(0)" ::: "memory");
    __builtin_amdgcn_s_barrier();
    asm volatile("s_waitcnt lgkmcnt(0)" ::: "memory");   // epilogue LDS reuse safety
#undef STAGE
}

// ---------------- W' builder: W'[o,i] = q[o,i]*qs + sum_r Ld[o,r]*Rt[i,r] ----
__global__ void __launch_bounds__(512, 2)
lr_w_kernel(const __bf16* __restrict__ Ld,   // [4096][256]
            const __bf16* __restrict__ Rt,   // [4096][256]
            const int*   __restrict__ qv,    // [4096][4096]
            const float* __restrict__ qs,    // [4096][32]
            unsigned short* __restrict__ Wp) // [4096][4096] bf16
{
    __shared__ __bf16 sm[2][2][2][8192];   // 128 KiB
    const int tid  = threadIdx.x;
    const int lane = tid & 63;
    const int wave = tid >> 6;
    const int wr = wave >> 2;
    const int wc = wave & 3;

    const int bid = blockIdx.x;
    const int cpx = gridDim.x >> 3;
    const int s   = (bid & 7) * cpx + (bid >> 3);
    const int mBase = (s >> 4) * 256;   // o
    const int nBase = (s & 15) * 256;   // i

    f32x4 acc[8][4] = {};
    __bf16* smp = &sm[0][0][0][0];
    run_pipeline(Ld, Rt, 256, 4, mBase, nBase, wave, lane, wr, wc, smp, acc);

    float* lsm = (float*)smp;            // [128][256] fp32 view
    const int cn = lane & 15;
    const int rg = (lane >> 4) * 4;

    #pragma unroll 1
    for (int h = 0; h < 2; ++h) {
        #pragma unroll
        for (int mf4 = 0; mf4 < 4; ++mf4) {
            const int mf = h * 4 + mf4;
            #pragma unroll
            for (int nf = 0; nf < 4; ++nf) {
                #pragma unroll
                for (int r = 0; r < 4; ++r) {
                    const int lrowi = wr * 64 + mf4 * 16 + rg + r;
                    const int col = (wc * 64 + nf * 16 + cn) ^ (((lrowi >> 2) & 1) << 4);
                    lsm[lrowi * 256 + col] = acc[mf][nf][r];
                }
            }
        }
        __syncthreads();
        #pragma unroll 2
        for (int it = 0; it < 8; ++it) {
            const int linear = it * 512 + tid;       // 0..4095
            const int lrowi  = linear >> 5;          // 0..127
            const int coff   = (linear & 31) * 8;
            const int grow = mBase + ((lrowi >> 6) * 128) + h * 64 + (lrowi & 63);
            const int gcol = nBase + coff;
            const int cswz = (coff * 4) ^ (((lrowi >> 2) & 1) << 6);
            const float* lp = (const float*)((const char*)lsm + (size_t)lrowi * 1024 + cswz);
            f32x4 lo = *(const f32x4*)lp;
            f32x4 hi = *(const f32x4*)(lp + 4);
            const float sc = qs[grow * 32 + (gcol >> 7)];
            const int4 qa = *(const int4*)&qv[(size_t)grow * 4096 + gcol];
            const int4 qb = *(const int4*)&qv[(size_t)grow * 4096 + gcol + 4];
            union { unsigned short u[8]; uint4 x; } w;
            w.u[0] = f2bf(qa.x * sc + lo[0]);
            w.u[1] = f2bf(qa.y * sc + lo[1]);
            w.u[2] = f2bf(qa.z * sc + lo[2]);
            w.u[3] = f2bf(qa.w * sc + lo[3]);
            w.u[4] = f2bf(qb.x * sc + hi[0]);
            w.u[5] = f2bf(qb.y * sc + hi[1]);
            w.u[6] = f2bf(qb.z * sc + hi[2]);
            w.u[7] = f2bf(qb.w * sc + hi[3]);
            *(uint4*)&Wp[(size_t)grow * 4096 + gcol] = w.x;
        }
        __syncthreads();
    }
}

// ---------------- main GEMM: out[T,DO] = xb @ Wp^T + bias ----------------
// XCD partition: 8x8 block squares per XCD (B-panels fetched 4x not 8x).
__global__ void __launch_bounds__(512, 2)
gemm256_kernel(const __bf16* __restrict__ A, const __bf16* __restrict__ B,
               int lda, int nt,
               const float* __restrict__ bias, float* __restrict__ out,
               int ldo) {
    __shared__ __bf16 sm[2][2][2][8192];   // 128 KiB

    const int tid  = threadIdx.x;
    const int lane = tid & 63;
    const int wave = tid >> 6;
    const int wr = wave >> 2;
    const int wc = wave & 3;

    // grid = 512 = 32(by) x 16(bx); XCD x owns the 8x8 square
    // by in [8*(x>>1), +8), bx in [8*(x&1), +8). Bijective.
    const int bid = blockIdx.x;
    const int xcd = bid & 7;
    const int u   = bid >> 3;            // 0..63
    const int bx  = (xcd & 1) * 8 + (u & 7);
    const int by  = (xcd >> 1) * 8 + (u >> 3);
    const int mBase = by * 256;
    const int nBase = bx * 256;

    f32x4 acc[8][4] = {};
    __bf16* smp = &sm[0][0][0][0];
    run_pipeline(A, B, lda, nt, mBase, nBase, wave, lane, wr, wc, smp, acc);

    // epilogue: C/D layout col = lane&15, row = (lane>>4)*4 + reg
    const int cn = lane & 15;
    const int rg = (lane >> 4) * 4;
    const int row0 = mBase + wr * 128 + rg;
    const int col0 = nBase + wc * 64 + cn;
    #pragma unroll
    for (int nf = 0; nf < 4; ++nf) {
        const int o = col0 + nf * 16;
        const float bv = bias[o];
        #pragma unroll
        for (int mf = 0; mf < 8; ++mf) {
            const int t0 = row0 + mf * 16;
            #pragma unroll
            for (int r = 0; r < 4; ++r)
                out[(size_t)(t0 + r) * ldo + o] = acc[mf][nf][r] + bv;
        }
    }
}

extern "C" void kernel_launch(void* const* d_in, const int* in_sizes, int n_in,
                              void* d_out, int out_size, void* d_ws, size_t ws_size,
                              hipStream_t stream) {
    const float* x    = (const float*)d_in[0];
    const int*   qv   = (const int*)d_in[1];
    const float* qs   = (const float*)d_in[2];
    const int*   lv   = (const int*)d_in[3];
    const float* ls   = (const float*)d_in[4];
    const int*   rv   = (const int*)d_in[5];
    const float* rs   = (const float*)d_in[6];
    const float* bias = (const float*)d_in[7];
    float* out = (float*)d_out;

    const int T = 8192, DI = 4096, DO = 4096;

    char* ws = (char*)d_ws;
    unsigned short* xb = (unsigned short*)(ws);                 // 8192x4096 bf16 = 64 MiB
    unsigned short* Wp = (unsigned short*)(ws + 67108864);      // 4096x4096 bf16 = 32 MiB
    unsigned short* Ld = (unsigned short*)(ws + 100663296);     // 4096x 256 bf16 =  2 MiB
    unsigned short* Rt = (unsigned short*)(ws + 102760448);     // 4096x 256 bf16 =  2 MiB

    {   // fused prep: cast x, dequant L, dequant+transpose R
        prep_kernel<<<17408, 256, 0, stream>>>(
            x, xb, lv, ls, Ld, rv, rs, Rt);
    }
    {   // Wp = Q*scale + Ld @ Rt^T   (fused dequant epilogue)
        lr_w_kernel<<<256, 512, 0, stream>>>(
            (const __bf16*)Ld, (const __bf16*)Rt, qv, qs, Wp);
    }
    {   // out = xb @ Wp^T + bias
        int nblocks = (DO / 256) * (T / 256);   // 512
        gemm256_kernel<<<nblocks, 512, 0, stream>>>(
            (const __bf16*)xb, (const __bf16*)Wp, DI, DI / 64,
            bias, out, DO);
    }
}

// Round 5
// 886.701 us; speedup vs baseline: 1.0927x; 1.0927x over previous
//
#include <hip/hip_runtime.h>
#include <cstdint>
#include <cstddef>

typedef float f32x4 __attribute__((ext_vector_type(4)));
typedef __bf16 bf16x8 __attribute__((ext_vector_type(8)));

__device__ __forceinline__ unsigned short f2bf(float f) {
    unsigned int u = __float_as_uint(f);
    u += 0x7fffu + ((u >> 16) & 1u);   // round-to-nearest-even
    return (unsigned short)(u >> 16);
}

__device__ __forceinline__ void async_copy16(const void* g, void* l) {
    __builtin_amdgcn_global_load_lds(
        (__attribute__((address_space(1))) void*)(g),
        (__attribute__((address_space(3))) void*)(l), 16, 0, 0);
}

// ---------------- fused prep kernel ----------------
// blocks [0,16384): cast x fp32->bf16 (8192x4096)
// blocks [16384,16896): dequant L -> Ld [4096][256]
// blocks [16896,17408): dequant R + transpose -> Rt [4096][256]
__global__ void prep_kernel(const float* __restrict__ x,
                            unsigned short* __restrict__ xb,
                            const int* __restrict__ lv,
                            const float* __restrict__ ls,
                            unsigned short* __restrict__ Ld,
                            const int* __restrict__ rv,
                            const float* __restrict__ rs,
                            unsigned short* __restrict__ Rt) {
    const int bid = blockIdx.x;
    const int tid = threadIdx.x;
    if (bid < 16384) {
        const int i = bid * 256 + tid;
        const float4* xv = (const float4*)x;
        float4 a = xv[2 * (size_t)i];
        float4 b = xv[2 * (size_t)i + 1];
        union { unsigned short u[8]; uint4 v; } r;
        r.u[0] = f2bf(a.x); r.u[1] = f2bf(a.y); r.u[2] = f2bf(a.z); r.u[3] = f2bf(a.w);
        r.u[4] = f2bf(b.x); r.u[5] = f2bf(b.y); r.u[6] = f2bf(b.z); r.u[7] = f2bf(b.w);
        ((uint4*)xb)[i] = r.v;
    } else if (bid < 16896) {
        const int i = (bid - 16384) * 256 + tid;     // 0..131071
        const int e = i * 8;
        const int row = e >> 8;
        const int col = e & 255;
        const float sc = ls[row * 2 + (col >> 7)];
        int4 a = ((const int4*)lv)[2 * (size_t)i];
        int4 b = ((const int4*)lv)[2 * (size_t)i + 1];
        union { unsigned short u[8]; uint4 v; } r;
        r.u[0] = f2bf(a.x * sc); r.u[1] = f2bf(a.y * sc);
        r.u[2] = f2bf(a.z * sc); r.u[3] = f2bf(a.w * sc);
        r.u[4] = f2bf(b.x * sc); r.u[5] = f2bf(b.y * sc);
        r.u[6] = f2bf(b.z * sc); r.u[7] = f2bf(b.w * sc);
        ((uint4*)Ld)[i] = r.v;
    } else {
        const int g = (bid - 16896) * 256 + tid;     // 0..131071
        const int i  = g & 4095;
        const int r0 = (g >> 12) << 3;               // 0,8,...,248
        const int grp = i >> 7;
        union { unsigned short u[8]; uint4 v; } w;
        #pragma unroll
        for (int k = 0; k < 8; ++k) {
            const int r = r0 + k;
            const float sc = rs[r * 32 + grp];
            w.u[k] = f2bf((float)rv[(size_t)r * 4096 + i] * sc);
        }
        *(uint4*)&Rt[(size_t)i * 256 + r0] = w.v;
    }
}

// ---------------- 256x256 8-phase pipelined GEMM core (ROTATED, R5) ----------
// R5 changes vs R4: (a) launch_bounds min-waves 2->1 (the R4 regression was a
// forced 128-VGPR cap -> ~110 regs spilled; LDS already pins occupancy at
// 1 block/CU = 2 waves/SIMD which supports 256 VGPR); (b) bLo single-buffered:
// t1's bLo read moved to p4 AFTER q10's MFMA issues (in-order issue => safe
// reuse), cutting fragment demand to 96 VGPR (total ~245 <= 256).
// Phase map (steady state, quadrant order q00,q01,q11,q10 per tile):
//  p1: MFMA q00(t0)           | STAGE A1(t1,s1)
//  p2: MFMA q01(t0)           | STAGE B0(p2,s0)
//  p3: MFMA q11(t0) vmcnt(2) RD aLo<-Ah1      | STAGE B1(p2,s0)
//  p4: MFMA q10(t0)          RD bLo,bHi<-Bh1  | STAGE A0(p2,s0)
//  p5: MFMA q00(t1)          RD aHi<-Ah1      | STAGE A1(p2,s0)
//  p6: MFMA q01(t1)           | STAGE B0(p3,s1)
//  p7: MFMA q11(t1) vmcnt(2) RD aLo<-Ah0      | STAGE B1(p3,s1)
//  p8: MFMA q10(t1)          RD bLo,bHi<-Bh0  | STAGE A0(p3,s1)
// vmcnt ledger: at p3/p7 checkpoint, 2 ops issued after the consumed tile's
// A1 -> vmcnt(2) retires exactly through that tile. WAR: every read issues
// >=2 barriers before its slot's overwriting STAGE.

#define SM_OFF(slot_, mat_, half_) ((((slot_) * 2 + (mat_)) * 2 + (half_)) * 8192)

#define MFMA_QUAD(MG, NG, AA, BB)                                           \
    _Pragma("unroll")                                                       \
    for (int m_ = 0; m_ < 4; ++m_)                                          \
        _Pragma("unroll")                                                   \
        for (int n_ = 0; n_ < 2; ++n_)                                      \
            _Pragma("unroll")                                               \
            for (int k_ = 0; k_ < 2; ++k_)                                  \
                acc[(MG)*4 + m_][(NG)*2 + n_] =                             \
                    __builtin_amdgcn_mfma_f32_16x16x32_bf16(                \
                        AA[m_][k_], BB[n_][k_],                             \
                        acc[(MG)*4 + m_][(NG)*2 + n_], 0, 0, 0)

#define RD_A(dst_, src_, base_)                                             \
    _Pragma("unroll")                                                       \
    for (int m_ = 0; m_ < 4; ++m_) {                                        \
        dst_[m_][0] = *(const bf16x8*)((src_) + ((base_) + m_) * 1024 + aoff0); \
        dst_[m_][1] = *(const bf16x8*)((src_) + ((base_) + m_) * 1024 + aoff1); \
    }

#define RD_B(dst_, src_, base_)                                             \
    _Pragma("unroll")                                                       \
    for (int n_ = 0; n_ < 2; ++n_) {                                        \
        dst_[n_][0] = *(const bf16x8*)((src_) + ((base_) + n_) * 1024 + aoff0); \
        dst_[n_][1] = *(const bf16x8*)((src_) + ((base_) + n_) * 1024 + aoff1); \
    }

#define PH_TOP()                                                            \
    asm volatile("s_waitcnt lgkmcnt(0)" ::: "memory");                      \
    __builtin_amdgcn_sched_barrier(0)

#define PH_END() __builtin_amdgcn_s_barrier()

__device__ __forceinline__ void run_pipeline(
    const __bf16* __restrict__ A, const __bf16* __restrict__ B,
    const int lda, const int nt,
    const int mBase, const int nBase,
    const int wave, const int lane, const int wr, const int wc,
    __bf16* smp, f32x4 (&acc)[8][4])
{
    const int lrow  = lane >> 3;
    const int lcol  = (((lane & 7) ^ lrow) & 7) * 8;
    const int soff0 = (wave * 8 + lrow) * lda + lcol;
    const size_t dsoff = (size_t)64 * lda;           // second-load lane delta

    const __bf16* gA0 = A + (size_t)mBase * lda + soff0;
    const __bf16* gA1 = gA0 + (size_t)128 * lda;
    const __bf16* gB0 = B + (size_t)nBase * lda + soff0;
    const __bf16* gB1 = gB0 + (size_t)128 * lda;

    const int aoff0 = (lane & 15) * 64 + ((((lane >> 4))     ^ (lane & 7)) * 8);
    const int aoff1 = (lane & 15) * 64 + (((4 + (lane >> 4)) ^ (lane & 7)) * 8);

    const __bf16* Ah0 = smp + SM_OFF(0, 0, wr);
    const __bf16* Ah1 = smp + SM_OFF(1, 0, wr);
    const __bf16* Bh0 = smp + SM_OFF(0, 1, wc >> 1) + (wc & 1) * 4096;
    const __bf16* Bh1 = smp + SM_OFF(1, 1, wc >> 1) + (wc & 1) * 4096;

#define STAGE(gp_, tile_, slot_, mat_, half_) do {                           \
        const __bf16* g_ = (gp_) + (size_t)(tile_) * 64;                     \
        __bf16* d_ = smp + SM_OFF(slot_, mat_, half_);                       \
        async_copy16(g_,         d_ + wave * 512);                           \
        async_copy16(g_ + dsoff, d_ + (wave + 8) * 512);                     \
    } while (0)

    // prologue: tile0 [B0,B1,A0,A1], tile1 [B0,B1,A0] = 7 halves (14 loads)
    STAGE(gB0, 0, 0, 1, 0);
    STAGE(gB1, 0, 0, 1, 1);
    STAGE(gA0, 0, 0, 0, 0);
    STAGE(gA1, 0, 0, 0, 1);
    STAGE(gB0, 1, 1, 1, 0);
    STAGE(gB1, 1, 1, 1, 1);
    STAGE(gA0, 1, 1, 0, 0);
    asm volatile("s_waitcnt vmcnt(6)" ::: "memory");   // tile0 fully resident
    __builtin_amdgcn_s_barrier();

    bf16x8 aLo[4][2], aHi[4][2], bLo[2][2], bHi[2][2];

    // pre-issue phase-1 reads (t0, slot0)
    RD_A(aLo, Ah0, 0);
    RD_B(bLo, Bh0, 0);

    const int niter = nt >> 1;
    #pragma unroll 1
    for (int i = 0; i < niter; ++i) {
        const int t1 = 2 * i + 1;
        int p2 = 2 * i + 2; if (p2 >= nt) p2 = nt - 2;   // even -> slot0
        int p3 = 2 * i + 3; if (p3 >= nt) p3 = nt - 1;   // odd  -> slot1

        // ---- phase 1: q00(t0) ----
        PH_TOP();
        __builtin_amdgcn_s_setprio(1);
        MFMA_QUAD(0, 0, aLo, bLo);
        __builtin_amdgcn_s_setprio(0);
        RD_B(bHi, Bh0, 2);
        STAGE(gA1, t1, 1, 0, 1);
        PH_END();

        // ---- phase 2: q01(t0) ----
        PH_TOP();
        __builtin_amdgcn_s_setprio(1);
        MFMA_QUAD(0, 1, aLo, bHi);
        __builtin_amdgcn_s_setprio(0);
        RD_A(aHi, Ah0, 4);
        STAGE(gB0, p2, 0, 1, 0);
        PH_END();

        // ---- phase 3: q11(t0) + checkpoint + t1 A-low reads ----
        PH_TOP();
        __builtin_amdgcn_s_setprio(1);
        MFMA_QUAD(1, 1, aHi, bHi);
        __builtin_amdgcn_s_setprio(0);
        asm volatile("s_waitcnt vmcnt(2)" ::: "memory");  // t1 fully resident
        RD_A(aLo, Ah1, 0);
        STAGE(gB1, p2, 0, 1, 1);
        PH_END();

        // ---- phase 4: q10(t0) + t1 B reads (after bLo's last consumer) ----
        PH_TOP();
        __builtin_amdgcn_s_setprio(1);
        MFMA_QUAD(1, 0, aHi, bLo);
        __builtin_amdgcn_s_setprio(0);
        RD_B(bLo, Bh1, 0);
        RD_B(bHi, Bh1, 2);
        STAGE(gA0, p2, 0, 0, 0);
        PH_END();

        // ---- phase 5: q00(t1) ----
        PH_TOP();
        __builtin_amdgcn_s_setprio(1);
        MFMA_QUAD(0, 0, aLo, bLo);
        __builtin_amdgcn_s_setprio(0);
        RD_A(aHi, Ah1, 4);
        STAGE(gA1, p2, 0, 0, 1);
        PH_END();

        // ---- phase 6: q01(t1) ----
        PH_TOP();
        __builtin_amdgcn_s_setprio(1);
        MFMA_QUAD(0, 1, aLo, bHi);
        __builtin_amdgcn_s_setprio(0);
        STAGE(gB0, p3, 1, 1, 0);
        PH_END();

        // ---- phase 7: q11(t1) + checkpoint + next-t0 A-low reads ----
        PH_TOP();
        __builtin_amdgcn_s_setprio(1);
        MFMA_QUAD(1, 1, aHi, bHi);
        __builtin_amdgcn_s_setprio(0);
        asm volatile("s_waitcnt vmcnt(2)" ::: "memory");  // next t0 resident
        RD_A(aLo, Ah0, 0);
        STAGE(gB1, p3, 1, 1, 1);
        PH_END();

        // ---- phase 8: q10(t1) + next-t0 B reads ----
        PH_TOP();
        __builtin_amdgcn_s_setprio(1);
        MFMA_QUAD(1, 0, aHi, bLo);
        __builtin_amdgcn_s_setprio(0);
        RD_B(bLo, Bh0, 0);
        RD_B(bHi, Bh0, 2);
        STAGE(gA0, p3, 1, 0, 0);
        PH_END();
    }

    asm volatile("s_waitcnt vmcnt(0)" ::: "memory");
    __builtin_amdgcn_s_barrier();
    asm volatile("s_waitcnt lgkmcnt(0)" ::: "memory");   // epilogue LDS reuse safety
#undef STAGE
}

// ---------------- W' builder: W'[o,i] = q[o,i]*qs + sum_r Ld[o,r]*Rt[i,r] ----
__global__ void __launch_bounds__(512, 1)
lr_w_kernel(const __bf16* __restrict__ Ld,   // [4096][256]
            const __bf16* __restrict__ Rt,   // [4096][256]
            const int*   __restrict__ qv,    // [4096][4096]
            const float* __restrict__ qs,    // [4096][32]
            unsigned short* __restrict__ Wp) // [4096][4096] bf16
{
    __shared__ __bf16 sm[2][2][2][8192];   // 128 KiB
    const int tid  = threadIdx.x;
    const int lane = tid & 63;
    const int wave = tid >> 6;
    const int wr = wave >> 2;
    const int wc = wave & 3;

    const int bid = blockIdx.x;
    const int cpx = gridDim.x >> 3;
    const int s   = (bid & 7) * cpx + (bid >> 3);
    const int mBase = (s >> 4) * 256;   // o
    const int nBase = (s & 15) * 256;   // i

    f32x4 acc[8][4] = {};
    __bf16* smp = &sm[0][0][0][0];
    run_pipeline(Ld, Rt, 256, 4, mBase, nBase, wave, lane, wr, wc, smp, acc);

    float* lsm = (float*)smp;            // [128][256] fp32 view
    const int cn = lane & 15;
    const int rg = (lane >> 4) * 4;

    #pragma unroll 1
    for (int h = 0; h < 2; ++h) {
        #pragma unroll
        for (int mf4 = 0; mf4 < 4; ++mf4) {
            const int mf = h * 4 + mf4;
            #pragma unroll
            for (int nf = 0; nf < 4; ++nf) {
                #pragma unroll
                for (int r = 0; r < 4; ++r) {
                    const int lrowi = wr * 64 + mf4 * 16 + rg + r;
                    const int col = (wc * 64 + nf * 16 + cn) ^ (((lrowi >> 2) & 1) << 4);
                    lsm[lrowi * 256 + col] = acc[mf][nf][r];
                }
            }
        }
        __syncthreads();
        #pragma unroll 2
        for (int it = 0; it < 8; ++it) {
            const int linear = it * 512 + tid;       // 0..4095
            const int lrowi  = linear >> 5;          // 0..127
            const int coff   = (linear & 31) * 8;
            const int grow = mBase + ((lrowi >> 6) * 128) + h * 64 + (lrowi & 63);
            const int gcol = nBase + coff;
            const int cswz = (coff * 4) ^ (((lrowi >> 2) & 1) << 6);
            const float* lp = (const float*)((const char*)lsm + (size_t)lrowi * 1024 + cswz);
            f32x4 lo = *(const f32x4*)lp;
            f32x4 hi = *(const f32x4*)(lp + 4);
            const float sc = qs[grow * 32 + (gcol >> 7)];
            const int4 qa = *(const int4*)&qv[(size_t)grow * 4096 + gcol];
            const int4 qb = *(const int4*)&qv[(size_t)grow * 4096 + gcol + 4];
            union { unsigned short u[8]; uint4 x; } w;
            w.u[0] = f2bf(qa.x * sc + lo[0]);
            w.u[1] = f2bf(qa.y * sc + lo[1]);
            w.u[2] = f2bf(qa.z * sc + lo[2]);
            w.u[3] = f2bf(qa.w * sc + lo[3]);
            w.u[4] = f2bf(qb.x * sc + hi[0]);
            w.u[5] = f2bf(qb.y * sc + hi[1]);
            w.u[6] = f2bf(qb.z * sc + hi[2]);
            w.u[7] = f2bf(qb.w * sc + hi[3]);
            *(uint4*)&Wp[(size_t)grow * 4096 + gcol] = w.x;
        }
        __syncthreads();
    }
}

// ---------------- main GEMM: out[T,DO] = xb @ Wp^T + bias ----------------
// XCD partition: 8x8 block squares per XCD (B-panels fetched 4x not 8x).
__global__ void __launch_bounds__(512, 1)
gemm256_kernel(const __bf16* __restrict__ A, const __bf16* __restrict__ B,
               int lda, int nt,
               const float* __restrict__ bias, float* __restrict__ out,
               int ldo) {
    __shared__ __bf16 sm[2][2][2][8192];   // 128 KiB

    const int tid  = threadIdx.x;
    const int lane = tid & 63;
    const int wave = tid >> 6;
    const int wr = wave >> 2;
    const int wc = wave & 3;

    // grid = 512 = 32(by) x 16(bx); XCD x owns the 8x8 square
    const int bid = blockIdx.x;
    const int xcd = bid & 7;
    const int u   = bid >> 3;            // 0..63
    const int bx  = (xcd & 1) * 8 + (u & 7);
    const int by  = (xcd >> 1) * 8 + (u >> 3);
    const int mBase = by * 256;
    const int nBase = bx * 256;

    f32x4 acc[8][4] = {};
    __bf16* smp = &sm[0][0][0][0];
    run_pipeline(A, B, lda, nt, mBase, nBase, wave, lane, wr, wc, smp, acc);

    // epilogue: C/D layout col = lane&15, row = (lane>>4)*4 + reg
    const int cn = lane & 15;
    const int rg = (lane >> 4) * 4;
    const int row0 = mBase + wr * 128 + rg;
    const int col0 = nBase + wc * 64 + cn;
    #pragma unroll
    for (int nf = 0; nf < 4; ++nf) {
        const int o = col0 + nf * 16;
        const float bv = bias[o];
        #pragma unroll
        for (int mf = 0; mf < 8; ++mf) {
            const int t0 = row0 + mf * 16;
            #pragma unroll
            for (int r = 0; r < 4; ++r)
                out[(size_t)(t0 + r) * ldo + o] = acc[mf][nf][r] + bv;
        }
    }
}

extern "C" void kernel_launch(void* const* d_in, const int* in_sizes, int n_in,
                              void* d_out, int out_size, void* d_ws, size_t ws_size,
                              hipStream_t stream) {
    const float* x    = (const float*)d_in[0];
    const int*   qv   = (const int*)d_in[1];
    const float* qs   = (const float*)d_in[2];
    const int*   lv   = (const int*)d_in[3];
    const float* ls   = (const float*)d_in[4];
    const int*   rv   = (const int*)d_in[5];
    const float* rs   = (const float*)d_in[6];
    const float* bias = (const float*)d_in[7];
    float* out = (float*)d_out;

    const int T = 8192, DI = 4096, DO = 4096;

    char* ws = (char*)d_ws;
    unsigned short* xb = (unsigned short*)(ws);                 // 8192x4096 bf16 = 64 MiB
    unsigned short* Wp = (unsigned short*)(ws + 67108864);      // 4096x4096 bf16 = 32 MiB
    unsigned short* Ld = (unsigned short*)(ws + 100663296);     // 4096x 256 bf16 =  2 MiB
    unsigned short* Rt = (unsigned short*)(ws + 102760448);     // 4096x 256 bf16 =  2 MiB

    {   // fused prep: cast x, dequant L, dequant+transpose R
        prep_kernel<<<17408, 256, 0, stream>>>(
            x, xb, lv, ls, Ld, rv, rs, Rt);
    }
    {   // Wp = Q*scale + Ld @ Rt^T   (fused dequant epilogue)
        lr_w_kernel<<<256, 512, 0, stream>>>(
            (const __bf16*)Ld, (const __bf16*)Rt, qv, qs, Wp);
    }
    {   // out = xb @ Wp^T + bias
        int nblocks = (DO / 256) * (T / 256);   // 512
        gemm256_kernel<<<nblocks, 512, 0, stream>>>(
            (const __bf16*)xb, (const __bf16*)Wp, DI, DI / 64,
            bias, out, DO);
    }
}